// Round 3
// baseline (472.873 us; speedup 1.0000x reference)
//
#include <hip/hip_runtime.h>
#include <stdint.h>

// Spiking ConvColumn: temporal PWL-response conv + winner-takes-all.
//   input_spikes [16, 2, 64, 64, 100] fp32 (binary)
//   weight       [32, 2, 3, 3]        fp32 in [0,1]
//   output       [16, 32, 31, 31, 149] fp32 (one-hot spikes)
#define NXS 31
#define NYS 31
#define NTRAIN 18      // C_in * 3 * 3
#define NT_HALF 9
#define TBL_N 101      // prefix entries per row (exclusive prefix, 0..100)
#define TP 149         // output time steps
#define TT 100         // input time steps
#define NROWS (16 * 2 * 64 * 64)   // 131072 input pixel rows

// ---------------------------------------------------------------------------
// Kernel A: per-row packed prefix tables into d_ws.
// entry k = (C[k]<<16) | M[k]; C[k] = #spikes at times < k, M[k] = sum times.
// One row per thread; fully parallel, memory-bound.
// ---------------------------------------------------------------------------
__global__ __launch_bounds__(256) void build_tables(
    const float* __restrict__ in, uint32_t* __restrict__ ws)
{
    const int row = blockIdx.x * 256 + threadIdx.x;       // 0..131071
    const float4* src = (const float4*)(in + (size_t)row * TT); // 400B-aligned
    uint32_t* t = ws + (size_t)row * TBL_N;
    int c = 0, m = 0, u = 0;
#pragma unroll 5
    for (int ch = 0; ch < 25; ++ch) {
        float4 v = src[ch];
        t[u] = (uint32_t)((c << 16) | m); if (v.x > 0.5f) { c++; m += u; } u++;
        t[u] = (uint32_t)((c << 16) | m); if (v.y > 0.5f) { c++; m += u; } u++;
        t[u] = (uint32_t)((c << 16) | m); if (v.z > 0.5f) { c++; m += u; } u++;
        t[u] = (uint32_t)((c << 16) | m); if (v.w > 0.5f) { c++; m += u; } u++;
    }
    t[TT] = (uint32_t)((c << 16) | m);
}

// ---------------------------------------------------------------------------
// Kernel B: one site per 64-lane wave (one wave per block, no s_barrier wait
// on other waves). Lanes 0-31: 32 channels x trains 0-8; lanes 32-63: same
// channels x trains 9-17.
// ---------------------------------------------------------------------------
__global__ __launch_bounds__(64) void snn_wta(
    const uint32_t* __restrict__ ws,
    const float* __restrict__ weight,
    float* __restrict__ out)
{
    __shared__ uint32_t tbl[NTRAIN * TBL_N];   // 7.27 KB

    const int lane = threadIdx.x;
    const int half = lane >> 5;
    const int ch   = lane & 31;
    const int s_id = blockIdx.x;
    const int x = s_id % NXS;
    const int y = (s_id / NXS) % NYS;
    const int b = s_id / (NXS * NYS);

    // ---- stage 18 tables: 6 contiguous segments of 3 rows (w,w+1,w+2) ----
    // global row id = ((b*2+ci)*64 + 2y+ky)*64 + 2x ; trains (ci,ky,kx=0..2)
    // are contiguous in both global and LDS layouts.
#pragma unroll
    for (int seg = 0; seg < 6; ++seg) {
        const int ci = seg / 3, ky = seg % 3;
        const uint32_t* src = ws +
            (size_t)(((b * 2 + ci) * 64 + 2 * y + ky) * 64 + 2 * x) * TBL_N;
        uint32_t* dst = tbl + (ci * 9 + ky * 3) * TBL_N;
#pragma unroll
        for (int k = 0; k < 5; ++k) {
            int idx = k * 64 + lane;
            if (idx < 3 * TBL_N) dst[idx] = src[idx];
        }
    }
    __syncthreads();

    // ---- per-lane response params for this lane's 9 trains ----
    // r(tau) = tau/16 for tau <= m = floor(16w); (48w-tau)/32 for m<tau<=n;
    // n = ceil(48w)-1.
    float wA[NT_HALF]; int mA[NT_HALF], nA[NT_HALF];
    {
        const float* wrow = weight + ch * NTRAIN + half * NT_HALF;
#pragma unroll
        for (int j = 0; j < NT_HALF; ++j) {
            float w = wrow[j];
            float a48 = 48.0f * w;
            int m = (int)floorf(16.0f * w);
            int n = (int)ceilf(a48) - 1;
            if (n < m) n = m;
            wA[j] = a48; mA[j] = m; nA[j] = n;
        }
    }
    const uint32_t* Th = tbl + half * NT_HALF * TBL_N;

    // ---- jump-scan WTA (spike => dep=47 => next eligible at tp+48) ----
    uint64_t msk0 = 0, msk1 = 0;
    uint32_t msk2 = 0;
    int tp = 0;
    while (tp < TP) {
        const int t1 = tp - 1;
        const float ft1 = (float)t1;
        const int i0 = (tp < TT) ? tp : TT;   // wave-uniform -> LDS broadcast
        float pot = 0.0f;
#pragma unroll
        for (int j = 0; j < NT_HALF; ++j) {
            const uint32_t* tt = Th + j * TBL_N;
            int i1 = t1 - mA[j]; i1 = i1 < 0 ? 0 : (i1 > TT ? TT : i1);
            int i2 = t1 - nA[j]; i2 = i2 < 0 ? 0 : (i2 > TT ? TT : i2);
            uint32_t p0 = tt[i0];
            uint32_t p1 = tt[i1];
            uint32_t p2 = tt[i2];
            // rising: sum s[u]*(t1-u)/16, u in [t1-m, t1]
            float dc1 = (float)(int)((p0 >> 16) - (p1 >> 16));
            float dm1 = (float)(int)((p0 & 0xffffu) - (p1 & 0xffffu));
            // falling: sum s[u]*(48w-(t1-u))/32, u in [t1-n, t1-1-m]
            float dc2 = (float)(int)((p1 >> 16) - (p2 >> 16));
            float dm2 = (float)(int)((p1 & 0xffffu) - (p2 & 0xffffu));
            pot += (ft1 * dc1 - dm1) * 0.0625f;
            pot += ((wA[j] - ft1) * dc2 + dm2) * 0.03125f;
        }
        pot += __shfl_xor(pot, 32);           // combine the two train halves

        // argmax over 32 channels; ties -> lowest channel (jnp.argmax)
        float v = pot; int c = ch;
#pragma unroll
        for (int mk = 16; mk >= 1; mk >>= 1) {
            float vo = __shfl_xor(v, mk);
            int co   = __shfl_xor(c, mk);
            if (vo > v || (vo == v && co < c)) { v = vo; c = co; }
        }
        if (v > 5.4f) {
            if (c == ch) {
                if (tp < 64)       msk0 |= 1ull << tp;
                else if (tp < 128) msk1 |= 1ull << (tp - 64);
                else               msk2 |= 1u   << (tp - 128);
            }
            tp += 48;
        } else {
            tp += 1;
        }
    }

    // ---- dense coalesced write of all 32 channel rows (covers the zeros) ----
    const size_t base0 = ((size_t)(b * 32) * NXS * NYS + (size_t)y * NYS + x) * TP;
    const size_t cstride = (size_t)NXS * NYS * TP;  // 143189
#pragma unroll 4
    for (int c = 0; c < 32; ++c) {
        uint64_t a0 = __shfl((unsigned long long)msk0, c);
        uint64_t a1 = __shfl((unsigned long long)msk1, c);
        uint32_t a2 = __shfl((unsigned int)msk2, c);
        float* r = out + base0 + (size_t)c * cstride;
        r[lane]      = ((a0 >> lane) & 1ull) ? 1.0f : 0.0f;   // tp 0..63
        r[64 + lane] = ((a1 >> lane) & 1ull) ? 1.0f : 0.0f;   // tp 64..127
        if (lane < TP - 128)
            r[128 + lane] = ((a2 >> lane) & 1u) ? 1.0f : 0.0f; // tp 128..148
    }
}

extern "C" void kernel_launch(void* const* d_in, const int* in_sizes, int n_in,
                              void* d_out, int out_size, void* d_ws, size_t ws_size,
                              hipStream_t stream) {
    const float* in = (const float*)d_in[0];   // input_spikes
    const float* wt = (const float*)d_in[1];   // weight
    float* out = (float*)d_out;
    uint32_t* ws = (uint32_t*)d_ws;            // 131072 * 101 * 4 B = 53 MB

    hipLaunchKernelGGL(build_tables, dim3(NROWS / 256), dim3(256), 0, stream,
                       in, ws);
    hipLaunchKernelGGL(snn_wta, dim3(16 * NXS * NYS), dim3(64), 0, stream,
                       ws, wt, out);
}

// Round 4
// 450.346 us; speedup vs baseline: 1.0500x; 1.0500x over previous
//
#include <hip/hip_runtime.h>
#include <stdint.h>

// Spiking ConvColumn: temporal PWL-response conv + winner-takes-all.
//   input_spikes [16, 2, 64, 64, 100] fp32 (binary)
//   weight       [32, 2, 3, 3]        fp32 in [0,1]
//   output       [16, 32, 31, 31, 149] fp32 (one-hot spikes)
#define NXS 31
#define NYS 31
#define NTRAIN 18      // C_in * 3 * 3
#define NT_HALF 9
#define TBL_STRIDE 101 // 101 mod 32 = 5, gcd(5,32)=1 -> conflict-free rows
#define TP 149         // output time steps
#define TT 100         // input time steps
#define NROWSOUT (16 * 32 * NXS * NYS)   // 492032 output (site,channel) rows

// ---------------------------------------------------------------------------
// Kernel 1: fused tables + WTA. One site per 64-lane wave, 2 waves/block.
// Lanes 0-31: 32 channels x trains 0-8; lanes 32-63: same channels x 9-17.
// Output: per (site,channel) row a 149-bit spike mask (3 x u64) into d_ws.
// ---------------------------------------------------------------------------
__global__ __launch_bounds__(128) void snn_wta_masks(
    const float* __restrict__ in,
    const float* __restrict__ weight,
    uint64_t* __restrict__ msk)
{
    // packed prefix tables per site: entry k = (C[k]<<16) | M[k]
    // C[k] = #spikes at times < k, M[k] = sum of those spike times.
    __shared__ uint32_t tbl[2 * NTRAIN * TBL_STRIDE];

    const int tid  = threadIdx.x;
    const int wave = tid >> 6;
    const int lane = tid & 63;
    const int half = lane >> 5;
    const int ch   = lane & 31;
    const int s_id = blockIdx.x * 2 + wave;
    const int x = s_id % NXS;
    const int y = (s_id / NXS) % NYS;
    const int b = s_id / (NXS * NYS);

    uint32_t* T = tbl + wave * NTRAIN * TBL_STRIDE;

    // ---- per-lane response params (issue first: overlaps table build) ----
    // r(tau) = tau/16 for tau <= m = floor(16w); (48w-tau)/32 for m<tau<=n;
    // n = ceil(48w)-1.
    float wA[NT_HALF]; int mA[NT_HALF], nA[NT_HALF];
    {
        const float* wrow = weight + ch * NTRAIN + half * NT_HALF;
#pragma unroll
        for (int j = 0; j < NT_HALF; ++j) {
            float w = wrow[j];
            float a48 = 48.0f * w;
            int m = (int)floorf(16.0f * w);
            int n = (int)ceilf(a48) - 1;
            if (n < m) n = m;
            wA[j] = a48; mA[j] = m; nA[j] = n;
        }
    }

    // ---- phase 1: 18 lanes/wave build prefix tables (scalar LDS writes;
    // banks (5*tr + k) % 32 distinct across the 18 active lanes) ----
    if (lane < NTRAIN) {
        const int tr = lane;
        const int ci = tr / 9;
        const int ky = (tr % 9) / 3;
        const int kx = tr % 3;
        const int h  = 2 * y + ky;          // valid conv, spatial stride 2
        const int wc = 2 * x + kx;
        const float4* row = (const float4*)(in +
            (size_t)(((b * 2 + ci) * 64 + h) * 64 + wc) * TT); // 400B-aligned
        uint32_t* t = T + tr * TBL_STRIDE;
        int c_run = 0, m_run = 0, u = 0;
#pragma unroll 5
        for (int chunk = 0; chunk < 25; ++chunk) {
            float4 v = row[chunk];
            t[u] = (uint32_t)((c_run << 16) | m_run);
            if (v.x > 0.5f) { c_run++; m_run += u; } u++;
            t[u] = (uint32_t)((c_run << 16) | m_run);
            if (v.y > 0.5f) { c_run++; m_run += u; } u++;
            t[u] = (uint32_t)((c_run << 16) | m_run);
            if (v.z > 0.5f) { c_run++; m_run += u; } u++;
            t[u] = (uint32_t)((c_run << 16) | m_run);
            if (v.w > 0.5f) { c_run++; m_run += u; } u++;
        }
        t[TT] = (uint32_t)((c_run << 16) | m_run);
    }
    __syncthreads();

    const uint32_t* Th = T + half * NT_HALF * TBL_STRIDE;

    // ---- phase 2: jump-scan WTA (spike => dep=47 => next eligible tp+48) ----
    uint64_t msk0 = 0, msk1 = 0, msk2 = 0;
    int tp = 0;
    while (tp < TP) {
        const int t1 = tp - 1;
        const float ft1 = (float)t1;
        const int i0 = (tp < TT) ? tp : TT;   // wave-uniform -> LDS broadcast
        float pot = 0.0f;
#pragma unroll
        for (int j = 0; j < NT_HALF; ++j) {
            const uint32_t* tt = Th + j * TBL_STRIDE;
            int i1 = t1 - mA[j]; i1 = i1 < 0 ? 0 : (i1 > TT ? TT : i1);
            int i2 = t1 - nA[j]; i2 = i2 < 0 ? 0 : (i2 > TT ? TT : i2);
            uint32_t p0 = tt[i0];
            uint32_t p1 = tt[i1];
            uint32_t p2 = tt[i2];
            // rising: sum s[u]*(t1-u)/16, u in [t1-m, t1]
            float dc1 = (float)(int)((p0 >> 16) - (p1 >> 16));
            float dm1 = (float)(int)((p0 & 0xffffu) - (p1 & 0xffffu));
            // falling: sum s[u]*(48w-(t1-u))/32, u in [t1-n, t1-1-m]
            float dc2 = (float)(int)((p1 >> 16) - (p2 >> 16));
            float dm2 = (float)(int)((p1 & 0xffffu) - (p2 & 0xffffu));
            pot += (ft1 * dc1 - dm1) * 0.0625f;
            pot += ((wA[j] - ft1) * dc2 + dm2) * 0.03125f;
        }
        pot += __shfl_xor(pot, 32);           // combine the two train halves

        // argmax over 32 channels; ties -> lowest channel (jnp.argmax)
        float v = pot; int c = ch;
#pragma unroll
        for (int mk = 16; mk >= 1; mk >>= 1) {
            float vo = __shfl_xor(v, mk);
            int co   = __shfl_xor(c, mk);
            if (vo > v || (vo == v && co < c)) { v = vo; c = co; }
        }
        if (v > 5.4f) {
            if (c == ch) {
                if (tp < 64)       msk0 |= 1ull << tp;
                else if (tp < 128) msk1 |= 1ull << (tp - 64);
                else               msk2 |= 1ull << (tp - 128);
            }
            tp += 48;
        } else {
            tp += 1;
        }
    }

    // ---- epilogue: lanes 0-31 write this channel's 24-B mask record ----
    if (lane < 32) {
        const size_t r = ((size_t)(b * 32 + ch) * NXS + y) * NYS + x;
        uint64_t* rec = msk + 3 * r;
        rec[0] = msk0; rec[1] = msk1; rec[2] = msk2;
    }
}

// ---------------------------------------------------------------------------
// Kernel 2: linear streaming expansion of masks -> dense fp32 output.
// One wave per output row (149 floats); 3 coalesced dword stores.
// ---------------------------------------------------------------------------
__global__ __launch_bounds__(256) void fill_out(
    const uint64_t* __restrict__ msk,
    float* __restrict__ out)
{
    const int tid  = threadIdx.x;
    const int lane = tid & 63;
    const int r    = blockIdx.x * 4 + (tid >> 6);   // 492032 rows exactly
    const uint64_t* rec = msk + 3 * (size_t)r;      // same addr across wave
    const uint64_t w0 = rec[0];
    const uint64_t w1 = rec[1];
    const uint64_t w2 = rec[2];
    float* o = out + (size_t)r * TP;
    __builtin_nontemporal_store(((w0 >> lane) & 1ull) ? 1.0f : 0.0f, o + lane);
    __builtin_nontemporal_store(((w1 >> lane) & 1ull) ? 1.0f : 0.0f, o + 64 + lane);
    if (lane < TP - 128)
        __builtin_nontemporal_store(((w2 >> lane) & 1ull) ? 1.0f : 0.0f,
                                    o + 128 + lane);
}

extern "C" void kernel_launch(void* const* d_in, const int* in_sizes, int n_in,
                              void* d_out, int out_size, void* d_ws, size_t ws_size,
                              hipStream_t stream) {
    const float* in = (const float*)d_in[0];   // input_spikes
    const float* wt = (const float*)d_in[1];   // weight
    float* out = (float*)d_out;
    uint64_t* msk = (uint64_t*)d_ws;           // 492032 * 24 B = 11.8 MB

    const int n_sites = 16 * NXS * NYS;        // 15376, 2 sites per block
    hipLaunchKernelGGL(snn_wta_masks, dim3(n_sites / 2), dim3(128), 0, stream,
                       in, wt, msk);
    hipLaunchKernelGGL(fill_out, dim3(NROWSOUT / 4), dim3(256), 0, stream,
                       msk, out);
}

// Round 5
// 397.956 us; speedup vs baseline: 1.1883x; 1.1316x over previous
//
#include <hip/hip_runtime.h>
#include <stdint.h>

// Spiking ConvColumn: temporal PWL-response conv + winner-takes-all.
//   input_spikes [16, 2, 64, 64, 100] fp32 (binary)
//   weight       [32, 2, 3, 3]        fp32 in [0,1]
//   output       [16, 32, 31, 31, 149] fp32 (one-hot spikes)
#define NXS 31
#define NYS 31
#define TP 149         // output time steps
#define TT 100         // input time steps
#define TBL_N 101      // prefix entries per row
#define NROWS_BLK 30   // (ci 2) x (ky 3) x (col 5) rows shared by an x-pair

// Block = 2 waves = sites (x, x+1) sharing one table set (cols 4xp..4xp+4).
// Wave lane split: lanes 0-31 = 32 channels x trains 0-8 (ci=0);
// lanes 32-63 = same channels x trains 9-17 (ci=1).
// Table row layout: row = ci*15 + ky*5 + c, c = wc - 4*xp.
// Entry k = (C[k]<<16) | M[k]: C = #spikes before time k, M = sum of times.
__global__ __launch_bounds__(128) void snn_wta(
    const float* __restrict__ in,
    const float* __restrict__ weight,
    float* __restrict__ out)
{
    __shared__ uint32_t tbl[NROWS_BLK * TBL_N];   // 12120 B -> 13 blk/CU

    const int tid  = threadIdx.x;
    const int wave = tid >> 6;
    const int lane = tid & 63;
    const int half = lane >> 5;
    const int ch   = lane & 31;

    const int bi = blockIdx.x;
    const int xp = bi & 15;               // 16 x-pairs (last is singleton)
    const int y  = (bi >> 4) % NYS;
    const int b  = bi / (16 * NYS);
    const int x  = 2 * xp + wave;         // this wave's site (x==31 inactive)

    // ---- per-lane response params for 9 trains (jg = half*9 + j) ----
    // r(tau) = tau/16 for tau <= m = floor(16w); (48w-tau)/32 for m<tau<=n.
    float wA[9]; int mA[9], nA[9];
    {
        const float* wrow = weight + ch * 18 + half * 9;
#pragma unroll
        for (int j = 0; j < 9; ++j) {
            float w = wrow[j];
            float a48 = 48.0f * w;
            int m = (int)floorf(16.0f * w);
            int n = (int)ceilf(a48) - 1;
            if (n < m) n = m;
            wA[j] = a48; mA[j] = m; nA[j] = n;
        }
    }

    // ---- phase 1: wave w builds rows w*15..w*15+14 (ci == wave) ----
    // Banks (5*r + u) % 32 distinct across the 15 active lanes (gcd(5,32)=1).
    if (lane < 15) {
        const int ky = lane / 5;
        const int c  = lane % 5;
        const int h  = 2 * y + ky;            // valid conv, spatial stride 2
        const int wc = 4 * xp + c;
        if (wc < 64) {                        // xp=15,c=4 would be OOB
            const float4* row = (const float4*)(in +
                (size_t)(((b * 2 + wave) * 64 + h) * 64 + wc) * TT);
            uint32_t* t = tbl + (wave * 15 + ky * 5 + c) * TBL_N;
            int cr = 0, mr = 0, u = 0;
#pragma unroll 5
            for (int chunk = 0; chunk < 25; ++chunk) {
                float4 v = row[chunk];
                t[u] = (uint32_t)((cr << 16) | mr);
                if (v.x > 0.5f) { cr++; mr += u; } u++;
                t[u] = (uint32_t)((cr << 16) | mr);
                if (v.y > 0.5f) { cr++; mr += u; } u++;
                t[u] = (uint32_t)((cr << 16) | mr);
                if (v.z > 0.5f) { cr++; mr += u; } u++;
                t[u] = (uint32_t)((cr << 16) | mr);
                if (v.w > 0.5f) { cr++; mr += u; } u++;
            }
            t[TT] = (uint32_t)((cr << 16) | mr);
        }
    }
    __syncthreads();

    if (x < NXS) {
        // per-lane table base: trains jg=half*9+j -> ci=half, ky=j/3, kx=j%3,
        // col = kx + 2*wave.
        const uint32_t* Th = tbl + (half * 15 + 2 * wave) * TBL_N;

        // ---- phase 2: jump-scan WTA with packed-difference eval ----
        // i2 <= i1 <= i0 per train => packed sums/differences carry-free:
        // sum(M-fields) <= 9*4950 < 2^16, sum(C-fields) <= 900 < 2^16.
        uint64_t msk0 = 0, msk1 = 0, msk2 = 0;
        int tp = 1;                           // tp=0: empty windows, no spike
        while (tp < TP) {
            const int t1 = tp - 1;
            const float ft1 = (float)t1;
            const int i0 = (tp < TT) ? tp : TT;   // wave-uniform
            uint32_t P0 = 0, P1 = 0, P2 = 0;
            float F = 0.0f;                       // sum_j 48w_j * dc2_j
#pragma unroll
            for (int j = 0; j < 9; ++j) {
                const uint32_t* tt = Th + ((j / 3) * 5 + (j % 3)) * TBL_N;
                int i1 = t1 - mA[j]; i1 = i1 < 0 ? 0 : (i1 > TT ? TT : i1);
                int i2 = t1 - nA[j]; i2 = i2 < 0 ? 0 : (i2 > TT ? TT : i2);
                uint32_t p0 = tt[i0];             // broadcast (uniform idx)
                uint32_t p1 = tt[i1];
                uint32_t p2 = tt[i2];
                P0 += p0; P1 += p1; P2 += p2;
                F += wA[j] * (float)((p1 - p2) >> 16);
            }
            const uint32_t D1 = P0 - P1;          // rising window totals
            const uint32_t D2 = P1 - P2;          // falling window totals
            const float dc1 = (float)(D1 >> 16);
            const float dm1 = (float)(D1 & 0xffffu);
            const float dc2 = (float)(D2 >> 16);
            const float dm2 = (float)(D2 & 0xffffu);
            float pot = (ft1 * dc1 - dm1) * 0.0625f
                      + (F - ft1 * dc2 + dm2) * 0.03125f;
            pot += __shfl_xor(pot, 32);           // combine train halves

            if (__ballot(pot > 5.4f)) {           // any channel spikes?
                // argmax over 32 channels; ties -> lowest ch (jnp.argmax)
                float v = pot; int c = ch;
#pragma unroll
                for (int mk = 16; mk >= 1; mk >>= 1) {
                    float vo = __shfl_xor(v, mk);
                    int co   = __shfl_xor(c, mk);
                    if (vo > v || (vo == v && co < c)) { v = vo; c = co; }
                }
                if (c == ch) {
                    if (tp < 64)       msk0 |= 1ull << tp;
                    else if (tp < 128) msk1 |= 1ull << (tp - 64);
                    else               msk2 |= 1ull << (tp - 128);
                }
                tp += 48;                         // dep=47 refractory skip
            } else {
                tp += 1;
            }
        }

        // ---- epilogue: dense write of all 32 channel rows (hidden under
        // other waves' compute; covers the 0xAA poison with zeros) ----
        const size_t base0 =
            ((size_t)(b * 32) * NXS * NYS + (size_t)y * NYS + x) * TP;
        const size_t cstride = (size_t)NXS * NYS * TP;  // 143189
#pragma unroll 4
        for (int c = 0; c < 32; ++c) {
            uint64_t a0 = __shfl((unsigned long long)msk0, c);
            uint64_t a1 = __shfl((unsigned long long)msk1, c);
            uint64_t a2 = __shfl((unsigned long long)msk2, c);
            float* r = out + base0 + (size_t)c * cstride;
            r[lane]      = ((a0 >> lane) & 1ull) ? 1.0f : 0.0f;  // tp 0..63
            r[64 + lane] = ((a1 >> lane) & 1ull) ? 1.0f : 0.0f;  // tp 64..127
            if (lane < TP - 128)
                r[128 + lane] = ((a2 >> lane) & 1ull) ? 1.0f : 0.0f;
        }
    }
}

extern "C" void kernel_launch(void* const* d_in, const int* in_sizes, int n_in,
                              void* d_out, int out_size, void* d_ws, size_t ws_size,
                              hipStream_t stream) {
    const float* in = (const float*)d_in[0];   // input_spikes
    const float* wt = (const float*)d_in[1];   // weight
    float* out = (float*)d_out;

    // grid: 16 batches x 31 y x 16 x-pairs (pair 15 is a singleton: x=30)
    hipLaunchKernelGGL(snn_wta, dim3(16 * NYS * 16), dim3(128), 0, stream,
                       in, wt, out);
}